// Round 1
// 165.811 us; speedup vs baseline: 1.1067x; 1.1067x over previous
//
#include <hip/hip_runtime.h>
#include <math.h>

#define BB 8
#define SS 2048
#define DD 1024
#define W520 520   // padded row width of half-spectrum V1 (513 used)

__device__ __forceinline__ float2 cmul(float2 a, float2 b) {
    return make_float2(fmaf(a.x, b.x, -a.y * b.y), fmaf(a.x, b.y, a.y * b.x));
}

__device__ __forceinline__ void radix4(float2 c0, float2 c1, float2 c2, float2 c3,
                                       float2 w1, float2 w2, float2 w3,
                                       float2& o0, float2& o1, float2& o2, float2& o3) {
    float2 d0 = make_float2(c0.x + c2.x, c0.y + c2.y);
    float2 d1 = make_float2(c0.x - c2.x, c0.y - c2.y);
    float2 d2 = make_float2(c1.x + c3.x, c1.y + c3.y);
    float2 e  = make_float2(c1.x - c3.x, c1.y - c3.y);
    float2 d3 = make_float2(e.y, -e.x);   // -i*(c1-c3)
    o0 = make_float2(d0.x + d2.x, d0.y + d2.y);
    o1 = cmul(w1, make_float2(d1.x + d3.x, d1.y + d3.y));
    o2 = cmul(w2, make_float2(d0.x - d2.x, d0.y - d2.y));
    o3 = cmul(w3, make_float2(d1.x - d3.x, d1.y - d3.y));
}

// ---------------- K1a: partial sum of exp over s-chunks ----------------
__global__ __launch_bounds__(256) void k_sumexp_partial(const float* __restrict__ x,
                                                        float* __restrict__ partial) {
    int bid = blockIdx.x;                 // 256 blocks: b(8) x sc(8) x dt(4)
    int b  = bid >> 5;
    int sc = (bid >> 2) & 7;
    int dt = bid & 3;
    int d  = (dt << 8) + threadIdx.x;
    const float* xp = x + ((size_t)(b * SS + sc * 256)) * DD + d;
    float acc = 0.f;
    #pragma unroll 8
    for (int i = 0; i < 256; ++i)
        acc += __expf(xp[(size_t)i * DD]);
    partial[(b * 8 + sc) * DD + d] = acc;
}

// ---------------- K1b: combine partials -> reciprocal sums ----------------
__global__ __launch_bounds__(256) void k_sumexp_combine(const float* __restrict__ partial,
                                                        float* __restrict__ rsum) {
    int i = blockIdx.x * 256 + threadIdx.x;   // 8192 threads
    int b = i >> 10, d = i & (DD - 1);
    float s = 0.f;
    #pragma unroll
    for (int sc = 0; sc < 8; ++sc) s += partial[(b * 8 + sc) * DD + d];
    rsum[i] = 1.f / s;
}

// ---------------- K2: softmax finish + 1024-pt FFT along D ----------------
// one block per (b,s) row; writes visual and half-spectrum V1[0..512]
__global__ __launch_bounds__(256) void k_fft_d(const float* __restrict__ x,
                                               const float* __restrict__ rsum,
                                               float* __restrict__ visual,
                                               float2* __restrict__ V1) {
    __shared__ float2 bufA[DD];
    __shared__ float2 bufB[DD];
    __shared__ float2 tw[DD / 2];
    const int t = threadIdx.x;
    const int bid = blockIdx.x;            // b*2048 + s
    const int b = bid >> 11;

    #pragma unroll
    for (int i = 0; i < 2; ++i) {          // twiddle table W[t]=exp(-2pi i t/1024)
        int j = t + (i << 8);
        float sn, cs;
        __sincosf(-6.283185307179586f * (float)j / (float)DD, &sn, &cs);
        tw[j] = make_float2(cs, sn);
    }
    const float* xr = x + (size_t)bid * DD;
    const float* rs = rsum + b * DD;
    float* vr = visual + (size_t)bid * DD;
    #pragma unroll
    for (int c = 0; c < 4; ++c) {
        int d = t + (c << 8);
        float v = __expf(xr[d]) * rs[d];
        vr[d] = v;
        bufA[d] = make_float2(v, 0.f);
    }
    __syncthreads();

    float2* src = bufA; float2* dst = bufB;
    int m = 1;
    #pragma unroll
    for (int st = 0; st < 5; ++st) {       // 4^5 = 1024
        int k  = t & (m - 1);
        int jm = t - k;                    // j*m, < 256
        float2 c0 = src[k + jm];
        float2 c1 = src[k + jm + 256];
        float2 c2 = src[k + jm + 512];
        float2 c3 = src[k + jm + 768];
        float2 w1 = tw[jm];
        float2 w2 = tw[2 * jm];
        float2 w3 = cmul(w1, w2);
        float2 o0, o1, o2, o3;
        radix4(c0, c1, c2, c3, w1, w2, w3, o0, o1, o2, o3);
        int o = k + 4 * jm;
        dst[o]         = o0;
        dst[o + m]     = o1;
        dst[o + 2 * m] = o2;
        dst[o + 3 * m] = o3;
        float2* tmp = src; src = dst; dst = tmp;
        m <<= 2;
        __syncthreads();
    }
    float2* outp = V1 + (size_t)bid * W520;
    outp[t]       = src[t];
    outp[t + 256] = src[t + 256];
    if (t == 0) outp[512] = src[512];
}

// ---------------- K3: 2048-pt FFT along S for 4 columns, Re output + mirror ----------------
// 1024 threads/block (16 waves/CU at 1 block/CU) for latency hiding; same LDS footprint.
#define CSTR 2052   // padded column stride (float2) to spread LDS banks
__global__ __launch_bounds__(1024) void k_fft_s(const float2* __restrict__ V1,
                                                float* __restrict__ out) {
    __shared__ float2 lds[2 * 4 * CSTR + SS / 2];  // bufA(4 cols), bufB, tw -> 139.5 KB
    float2* bufA = lds;
    float2* bufB = lds + 4 * CSTR;
    float2* tw   = lds + 8 * CSTR;
    const int t = threadIdx.x;             // 0..1023
    const int bid = blockIdx.x;            // b*129 + g
    const int b = bid / 129;
    const int g = bid - b * 129;
    const int c = t & 3;                   // column in group
    const int q = t >> 2;                  // 0..255
    const int k2 = 4 * g + c;

    {   // W[t]=exp(-2pi i t/2048), 1024 entries, one per thread
        float sn, cs;
        __sincosf(-6.283185307179586f * (float)t / (float)SS, &sn, &cs);
        tw[t] = make_float2(cs, sn);
    }
    // load: two adjacent columns per float4 load (half the VMEM instructions)
    {
        const float4* src4 = (const float4*)(V1 + (size_t)b * SS * W520 + 4 * g);
        const int h  = t & 1;              // which column pair (2h, 2h+1)
        const int s0 = t >> 1;             // 0..511
        #pragma unroll
        for (int i = 0; i < 4; ++i) {
            int s = s0 + (i << 9);         // 0..2047
            float4 v = src4[(size_t)s * (W520 / 2) + h];
            bufA[(2 * h) * CSTR + s]     = make_float2(v.x, v.y);
            bufA[(2 * h + 1) * CSTR + s] = make_float2(v.z, v.w);
        }
    }
    __syncthreads();

    float2* sp = bufA; float2* dp = bufB;
    {   // radix-2 stage, m=1: 2*4^5 = 2048
        float2* sc_ = sp + c * CSTR;
        float4* d4  = (float4*)(dp + c * CSTR);   // 16B-aligned (CSTR even)
        #pragma unroll
        for (int i = 0; i < 4; ++i) {
            int idx = q + (i << 8);        // 0..1023
            float2 c0 = sc_[idx];
            float2 c1 = sc_[idx + 1024];
            float2 s0 = make_float2(c0.x + c1.x, c0.y + c1.y);
            float2 s1 = cmul(tw[idx], make_float2(c0.x - c1.x, c0.y - c1.y));
            d4[idx] = make_float4(s0.x, s0.y, s1.x, s1.y);   // ds_write_b128
        }
        float2* tmp = sp; sp = dp; dp = tmp;
        __syncthreads();
    }
    int m = 2;
    for (int st = 0; st < 5; ++st) {
        float2* sc_ = sp + c * CSTR;
        float2* dc_ = dp + c * CSTR;
        #pragma unroll
        for (int i = 0; i < 2; ++i) {
            int idx = q + (i << 8);        // 0..511
            int k  = idx & (m - 1);
            int jm = idx - k;              // < 512
            float2 c0 = sc_[k + jm];
            float2 c1 = sc_[k + jm + 512];
            float2 c2 = sc_[k + jm + 1024];
            float2 c3 = sc_[k + jm + 1536];
            float2 w1 = tw[jm];
            float2 w2 = tw[2 * jm];
            float2 w3 = cmul(w1, w2);
            float2 o0, o1, o2, o3;
            radix4(c0, c1, c2, c3, w1, w2, w3, o0, o1, o2, o3);
            int o = k + 4 * jm;
            dc_[o]         = o0;
            dc_[o + m]     = o1;
            dc_[o + 2 * m] = o2;
            dc_[o + 3 * m] = o3;
        }
        float2* tmp = sp; sp = dp; dp = tmp;
        m <<= 2;
        __syncthreads();
    }
    // result back in bufA (6 stages); write own column and Hermitian mirror
    const float2* res = sp + c * CSTR;
    float* outb = out + (size_t)b * SS * DD;
    const bool own = (k2 <= 512);
    const bool mir = (k2 >= 1 && k2 <= 511);
    #pragma unroll
    for (int i = 0; i < 8; ++i) {
        int k1 = q + (i << 8);
        if (own) outb[(size_t)k1 * DD + k2] = res[k1].x;
        if (mir) outb[(size_t)k1 * DD + (DD - k2)] = res[(SS - k1) & (SS - 1)].x;
    }
}

extern "C" void kernel_launch(void* const* d_in, const int* in_sizes, int n_in,
                              void* d_out, int out_size, void* d_ws, size_t ws_size,
                              hipStream_t stream) {
    const float* x = (const float*)d_in[0];
    float* out    = (float*)d_out;                        // Re(FFT2) : 16,777,216 floats
    float* visual = out + (size_t)BB * SS * DD;           // softmax  : 16,777,216 floats

    char* ws = (char*)d_ws;
    float2* V1     = (float2*)ws;                                        // 68,157,440 B
    float*  partial = (float*)(ws + (size_t)BB * SS * W520 * sizeof(float2));  // 256 KB
    float*  rsum    = partial + BB * 8 * DD;                             // 32 KB

    hipLaunchKernelGGL(k_sumexp_partial, dim3(256), dim3(256), 0, stream, x, partial);
    hipLaunchKernelGGL(k_sumexp_combine, dim3(32), dim3(256), 0, stream, partial, rsum);
    hipLaunchKernelGGL(k_fft_d, dim3(BB * SS), dim3(256), 0, stream, x, rsum, visual, V1);
    hipLaunchKernelGGL(k_fft_s, dim3(BB * 129), dim3(1024), 0, stream, V1, out);
}

// Round 2
// 148.517 us; speedup vs baseline: 1.2356x; 1.1164x over previous
//
#include <hip/hip_runtime.h>
#include <math.h>

#define BB 8
#define SS 2048
#define DD 1024
#define W520 520   // padded row width of half-spectrum V1 (513 used)

__device__ __forceinline__ float2 cmul(float2 a, float2 b) {
    return make_float2(fmaf(a.x, b.x, -a.y * b.y), fmaf(a.x, b.y, a.y * b.x));
}

// DIF/DIT-agnostic radix-4 butterfly: o_r = w_r * (sum_q x_q * (-i)^{qr}), w0=1
__device__ __forceinline__ void radix4(float2 c0, float2 c1, float2 c2, float2 c3,
                                       float2 w1, float2 w2, float2 w3,
                                       float2& o0, float2& o1, float2& o2, float2& o3) {
    float2 d0 = make_float2(c0.x + c2.x, c0.y + c2.y);
    float2 d1 = make_float2(c0.x - c2.x, c0.y - c2.y);
    float2 d2 = make_float2(c1.x + c3.x, c1.y + c3.y);
    float2 e  = make_float2(c1.x - c3.x, c1.y - c3.y);
    float2 d3 = make_float2(e.y, -e.x);   // -i*(c1-c3)
    o0 = make_float2(d0.x + d2.x, d0.y + d2.y);
    o1 = cmul(w1, make_float2(d1.x + d3.x, d1.y + d3.y));
    o2 = cmul(w2, make_float2(d0.x - d2.x, d0.y - d2.y));
    o3 = cmul(w3, make_float2(d1.x - d3.x, d1.y - d3.y));
}

// ---------------- K1a: partial sum of exp over s-chunks ----------------
__global__ __launch_bounds__(256) void k_sumexp_partial(const float* __restrict__ x,
                                                        float* __restrict__ partial) {
    int bid = blockIdx.x;                 // 256 blocks: b(8) x sc(8) x dt(4)
    int b  = bid >> 5;
    int sc = (bid >> 2) & 7;
    int dt = bid & 3;
    int d  = (dt << 8) + threadIdx.x;
    const float* xp = x + ((size_t)(b * SS + sc * 256)) * DD + d;
    float acc = 0.f;
    #pragma unroll 8
    for (int i = 0; i < 256; ++i)
        acc += __expf(xp[(size_t)i * DD]);
    partial[(b * 8 + sc) * DD + d] = acc;
}

// ---------------- K1b: combine partials -> reciprocal sums ----------------
__global__ __launch_bounds__(256) void k_sumexp_combine(const float* __restrict__ partial,
                                                        float* __restrict__ rsum) {
    int i = blockIdx.x * 256 + threadIdx.x;   // 8192 threads
    int b = i >> 10, d = i & (DD - 1);
    float s = 0.f;
    #pragma unroll
    for (int sc = 0; sc < 8; ++sc) s += partial[(b * 8 + sc) * DD + d];
    rsum[i] = 1.f / s;
}

// ---------------- K2: softmax finish + 1024-pt FFT along D ----------------
// one block per (b,s) row; writes visual and half-spectrum V1[0..512]
__global__ __launch_bounds__(256) void k_fft_d(const float* __restrict__ x,
                                               const float* __restrict__ rsum,
                                               float* __restrict__ visual,
                                               float2* __restrict__ V1) {
    __shared__ float2 bufA[DD];
    __shared__ float2 bufB[DD];
    __shared__ float2 tw[DD / 2];
    const int t = threadIdx.x;
    const int bid = blockIdx.x;            // b*2048 + s
    const int b = bid >> 11;

    #pragma unroll
    for (int i = 0; i < 2; ++i) {          // twiddle table W[t]=exp(-2pi i t/1024)
        int j = t + (i << 8);
        float sn, cs;
        __sincosf(-6.283185307179586f * (float)j / (float)DD, &sn, &cs);
        tw[j] = make_float2(cs, sn);
    }
    const float* xr = x + (size_t)bid * DD;
    const float* rs = rsum + b * DD;
    float* vr = visual + (size_t)bid * DD;
    #pragma unroll
    for (int c = 0; c < 4; ++c) {
        int d = t + (c << 8);
        float v = __expf(xr[d]) * rs[d];
        vr[d] = v;
        bufA[d] = make_float2(v, 0.f);
    }
    __syncthreads();

    float2* src = bufA; float2* dst = bufB;
    int m = 1;
    #pragma unroll
    for (int st = 0; st < 5; ++st) {       // 4^5 = 1024 (Stockham, natural-order out)
        int k  = t & (m - 1);
        int jm = t - k;                    // j*m, < 256
        float2 c0 = src[k + jm];
        float2 c1 = src[k + jm + 256];
        float2 c2 = src[k + jm + 512];
        float2 c3 = src[k + jm + 768];
        float2 w1 = tw[jm];
        float2 w2 = tw[2 * jm];
        float2 w3 = cmul(w1, w2);
        float2 o0, o1, o2, o3;
        radix4(c0, c1, c2, c3, w1, w2, w3, o0, o1, o2, o3);
        int o = k + 4 * jm;
        dst[o]         = o0;
        dst[o + m]     = o1;
        dst[o + 2 * m] = o2;
        dst[o + 3 * m] = o3;
        float2* tmp = src; src = dst; dst = tmp;
        m <<= 2;
        __syncthreads();
    }
    float2* outp = V1 + (size_t)bid * W520;
    outp[t]       = src[t];
    outp[t + 256] = src[t + 256];
    if (t == 0) outp[512] = src[512];
}

// ---------------- K3: 2048-pt FFT along S for 8 columns ----------------
// In-place DIF radix-4^5 x radix-2, single LDS buffer (139.5 KB), 1024 threads.
// Output emerges digit-reversed; permutation folded into the (already scattered)
// global write. Reads: 64B/row fully coalesced. Own writes: 32B aligned chunks.
#define CSTR 2052   // padded column stride (float2)
__global__ __launch_bounds__(1024) void k_fft_s(const float2* __restrict__ V1,
                                                float* __restrict__ out) {
    __shared__ float2 buf[8 * CSTR];       // 131,328 B
    __shared__ float2 tw[SS / 2];          // 8,192 B
    const int t = threadIdx.x;             // 0..1023
    const int bid = blockIdx.x;            // b*65 + g
    const int b = bid / 65;
    const int g = bid - b * 65;
    const int c = t & 7;                   // column in group (k2 = 8g + c)
    const int q = t >> 3;                  // 0..127

    {   // W[t] = exp(-2pi i t / 2048), 1024 entries
        float sn, cs;
        __sincosf(-6.283185307179586f * (float)t / (float)SS, &sn, &cs);
        tw[t] = make_float2(cs, sn);
    }
    // load 8 columns: 4 x float4 per row = 64B contiguous, perfectly coalesced
    {
        const float4* src4 = (const float4*)(V1 + (size_t)b * SS * W520 + 8 * g);
        const int h  = t & 3;              // which float4 of the row (covers cols 2h,2h+1)
        const int s0 = t >> 2;             // 0..255
        #pragma unroll
        for (int i = 0; i < 8; ++i) {
            int s = s0 + (i << 8);         // 0..2047
            float4 v = src4[(size_t)s * (W520 / 2) + h];
            buf[(2 * h) * CSTR + s]     = make_float2(v.x, v.y);
            buf[(2 * h + 1) * CSTR + s] = make_float2(v.z, v.w);
        }
    }
    __syncthreads();

    float2* bc = buf + c * CSTR;
    // 5 in-place DIF radix-4 stages: span m = 512,128,32,8,2 ; twiddle step ts = 512/m
    int m = 512, ts = 1;
    #pragma unroll
    for (int st = 0; st < 5; ++st) {
        #pragma unroll
        for (int i = 0; i < 4; ++i) {
            int u = q + (i << 7);          // butterfly index 0..511
            int j = u & (m - 1);
            int base = ((u - j) << 2) + j; // block base (4m-aligned) + j
            float2 x0 = bc[base];
            float2 x1 = bc[base + m];
            float2 x2 = bc[base + 2 * m];
            float2 x3 = bc[base + 3 * m];
            float2 w1 = tw[j * ts];
            float2 w2 = tw[2 * j * ts];
            float2 w3 = cmul(w1, w2);
            float2 o0, o1, o2, o3;
            radix4(x0, x1, x2, x3, w1, w2, w3, o0, o1, o2, o3);
            bc[base]         = o0;
            bc[base + m]     = o1;
            bc[base + 2 * m] = o2;
            bc[base + 3 * m] = o3;
        }
        m >>= 2; ts <<= 2;
        __syncthreads();
    }
    // final radix-2 stage (span 1, no twiddle)
    #pragma unroll
    for (int i = 0; i < 8; ++i) {
        int v = q + (i << 7);              // 0..1023
        float2 a = bc[2 * v];
        float2 d = bc[2 * v + 1];
        bc[2 * v]     = make_float2(a.x + d.x, a.y + d.y);
        bc[2 * v + 1] = make_float2(a.x - d.x, a.y - d.y);
    }
    __syncthreads();

    // write-out: position p holds frequency k = digitrev(p)
    float* outb = out + (size_t)b * SS * DD;
    const int k2 = 8 * g + c;
    const bool own = (k2 <= 512);
    const bool mir = (k2 >= 1 && k2 <= 511);
    const int mcol = DD - k2;
    #pragma unroll
    for (int i = 0; i < 16; ++i) {
        int p = q + (i << 7);              // 0..2047 (same p across the 8 cols of a lane-group)
        float re = bc[p].x;
        int k = (p >> 9) | (((p >> 7) & 3) << 2) | (((p >> 5) & 3) << 4)
              | (((p >> 3) & 3) << 6) | (((p >> 1) & 3) << 8) | ((p & 1) << 10);
        if (own) outb[(size_t)k * DD + k2] = re;                          // Re F[k][k2]
        if (mir) outb[(size_t)((SS - k) & (SS - 1)) * DD + mcol] = re;    // Hermitian mirror
    }
}

extern "C" void kernel_launch(void* const* d_in, const int* in_sizes, int n_in,
                              void* d_out, int out_size, void* d_ws, size_t ws_size,
                              hipStream_t stream) {
    const float* x = (const float*)d_in[0];
    float* out    = (float*)d_out;                        // Re(FFT2) : 16,777,216 floats
    float* visual = out + (size_t)BB * SS * DD;           // softmax  : 16,777,216 floats

    char* ws = (char*)d_ws;
    float2* V1     = (float2*)ws;                                        // 68,157,440 B
    float*  partial = (float*)(ws + (size_t)BB * SS * W520 * sizeof(float2));  // 256 KB
    float*  rsum    = partial + BB * 8 * DD;                             // 32 KB

    hipLaunchKernelGGL(k_sumexp_partial, dim3(256), dim3(256), 0, stream, x, partial);
    hipLaunchKernelGGL(k_sumexp_combine, dim3(32), dim3(256), 0, stream, partial, rsum);
    hipLaunchKernelGGL(k_fft_d, dim3(BB * SS), dim3(256), 0, stream, x, rsum, visual, V1);
    hipLaunchKernelGGL(k_fft_s, dim3(BB * 65), dim3(1024), 0, stream, V1, out);
}

// Round 3
// 138.848 us; speedup vs baseline: 1.3216x; 1.0696x over previous
//
#include <hip/hip_runtime.h>
#include <math.h>

#define BB 8
#define SS 2048
#define DD 1024
#define W520 520   // padded row width of half-spectrum V1 (cols 0..511 used; col0 packs (F0,F512))

__device__ __forceinline__ float2 cmul(float2 a, float2 b) {
    return make_float2(fmaf(a.x, b.x, -a.y * b.y), fmaf(a.x, b.y, a.y * b.x));
}

// radix-4 butterfly: o_r = w_r * (sum_q x_q * (-i)^{qr}), w0=1
__device__ __forceinline__ void radix4(float2 c0, float2 c1, float2 c2, float2 c3,
                                       float2 w1, float2 w2, float2 w3,
                                       float2& o0, float2& o1, float2& o2, float2& o3) {
    float2 d0 = make_float2(c0.x + c2.x, c0.y + c2.y);
    float2 d1 = make_float2(c0.x - c2.x, c0.y - c2.y);
    float2 d2 = make_float2(c1.x + c3.x, c1.y + c3.y);
    float2 e  = make_float2(c1.x - c3.x, c1.y - c3.y);
    float2 d3 = make_float2(e.y, -e.x);   // -i*(c1-c3)
    o0 = make_float2(d0.x + d2.x, d0.y + d2.y);
    o1 = cmul(w1, make_float2(d1.x + d3.x, d1.y + d3.y));
    o2 = cmul(w2, make_float2(d0.x - d2.x, d0.y - d2.y));
    o3 = cmul(w3, make_float2(d1.x - d3.x, d1.y - d3.y));
}

// ---------------- K1a: partial sum of exp over s-chunks ----------------
__global__ __launch_bounds__(256) void k_sumexp_partial(const float* __restrict__ x,
                                                        float* __restrict__ partial) {
    int bid = blockIdx.x;                 // 256 blocks: b(8) x sc(8) x dt(4)
    int b  = bid >> 5;
    int sc = (bid >> 2) & 7;
    int dt = bid & 3;
    int d  = (dt << 8) + threadIdx.x;
    const float* xp = x + ((size_t)(b * SS + sc * 256)) * DD + d;
    float acc = 0.f;
    #pragma unroll 8
    for (int i = 0; i < 256; ++i)
        acc += __expf(xp[(size_t)i * DD]);
    partial[(b * 8 + sc) * DD + d] = acc;
}

// ---------------- K1b: combine partials -> reciprocal sums ----------------
__global__ __launch_bounds__(256) void k_sumexp_combine(const float* __restrict__ partial,
                                                        float* __restrict__ rsum) {
    int i = blockIdx.x * 256 + threadIdx.x;   // 8192 threads
    int b = i >> 10, d = i & (DD - 1);
    float s = 0.f;
    #pragma unroll
    for (int sc = 0; sc < 8; ++sc) s += partial[(b * 8 + sc) * DD + d];
    rsum[i] = 1.f / s;
}

// ---------------- K2: softmax finish + 1024-pt FFT along D ----------------
// one block per (b,s) row; writes visual and half-spectrum.
// Column 0 of V1 packs (Re F[0], Re F[512]) — both are real for real input.
__global__ __launch_bounds__(256) void k_fft_d(const float* __restrict__ x,
                                               const float* __restrict__ rsum,
                                               float* __restrict__ visual,
                                               float2* __restrict__ V1) {
    __shared__ float2 bufA[DD];
    __shared__ float2 bufB[DD];
    __shared__ float2 tw[DD / 2];
    const int t = threadIdx.x;
    const int bid = blockIdx.x;            // b*2048 + s
    const int b = bid >> 11;

    #pragma unroll
    for (int i = 0; i < 2; ++i) {          // twiddle table W[t]=exp(-2pi i t/1024)
        int j = t + (i << 8);
        float sn, cs;
        __sincosf(-6.283185307179586f * (float)j / (float)DD, &sn, &cs);
        tw[j] = make_float2(cs, sn);
    }
    const float* xr = x + (size_t)bid * DD;
    const float* rs = rsum + b * DD;
    float* vr = visual + (size_t)bid * DD;
    #pragma unroll
    for (int c = 0; c < 4; ++c) {
        int d = t + (c << 8);
        float v = __expf(xr[d]) * rs[d];
        vr[d] = v;
        bufA[d] = make_float2(v, 0.f);
    }
    __syncthreads();

    float2* src = bufA; float2* dst = bufB;
    int m = 1;
    #pragma unroll
    for (int st = 0; st < 5; ++st) {       // 4^5 = 1024 (Stockham, natural-order out)
        int k  = t & (m - 1);
        int jm = t - k;                    // j*m, < 256
        float2 c0 = src[k + jm];
        float2 c1 = src[k + jm + 256];
        float2 c2 = src[k + jm + 512];
        float2 c3 = src[k + jm + 768];
        float2 w1 = tw[jm];
        float2 w2 = tw[2 * jm];
        float2 w3 = cmul(w1, w2);
        float2 o0, o1, o2, o3;
        radix4(c0, c1, c2, c3, w1, w2, w3, o0, o1, o2, o3);
        int o = k + 4 * jm;
        dst[o]         = o0;
        dst[o + m]     = o1;
        dst[o + 2 * m] = o2;
        dst[o + 3 * m] = o3;
        float2* tmp = src; src = dst; dst = tmp;
        m <<= 2;
        __syncthreads();
    }
    float2* outp = V1 + (size_t)bid * W520;
    // col 0 packs the two purely-real spectrum columns: (F[0].re, F[512].re)
    outp[t] = (t == 0) ? make_float2(src[0].x, src[512].x) : src[t];
    outp[t + 256] = src[t + 256];
}

// ---------------- K3: 2048-pt FFT along S for 8 columns ----------------
// In-place DIF radix-4^5 x radix-2, single LDS buffer (131.3 KB), 1024 threads.
// Twiddles computed on the fly (no LDS table -> no 8-way bank conflicts).
// Grid = 8 batches x 64 groups = 512 blocks = exactly 2 rounds at 1 block/CU.
#define CSTR 2052   // padded column stride (float2)

__device__ __forceinline__ int permS(int k) {   // LDS position p holding frequency k
    return ((k >> 10) & 1) | (((k >> 8) & 3) << 1) | (((k >> 6) & 3) << 3)
         | (((k >> 4) & 3) << 5) | (((k >> 2) & 3) << 7) | ((k & 3) << 9);
}

__global__ __launch_bounds__(1024) void k_fft_s(const float2* __restrict__ V1,
                                                float* __restrict__ out) {
    __shared__ float2 buf[8 * CSTR];       // 131,328 B
    const int t = threadIdx.x;             // 0..1023
    const int bid = blockIdx.x;            // b*64 + g
    const int b = bid >> 6;
    const int g = bid & 63;
    const int c = t & 7;                   // column in group (k2 = 8g + c)
    const int q = t >> 3;                  // 0..127

    // load 8 columns: 4 x float4 per row = 64B contiguous, perfectly coalesced
    {
        const float4* src4 = (const float4*)(V1 + (size_t)b * SS * W520 + 8 * g);
        const int h  = t & 3;              // which float4 of the row (covers cols 2h,2h+1)
        const int s0 = t >> 2;             // 0..255
        #pragma unroll
        for (int i = 0; i < 8; ++i) {
            int s = s0 + (i << 8);         // 0..2047
            float4 v = src4[(size_t)s * (W520 / 2) + h];
            buf[(2 * h) * CSTR + s]     = make_float2(v.x, v.y);
            buf[(2 * h + 1) * CSTR + s] = make_float2(v.z, v.w);
        }
    }
    __syncthreads();

    float2* bc = buf + c * CSTR;
    // 5 in-place DIF radix-4 stages: span m = 512,128,32,8,2 ; twiddle step ts = 512/m
    const float PI2_N = -6.283185307179586f / (float)SS;
    int m = 512, ts = 1;
    #pragma unroll
    for (int st = 0; st < 5; ++st) {
        #pragma unroll
        for (int i = 0; i < 4; ++i) {
            int u = q + (i << 7);          // butterfly index 0..511
            int j = u & (m - 1);
            int base = ((u - j) << 2) + j; // block base (4m-aligned) + j
            float2 x0 = bc[base];
            float2 x1 = bc[base + m];
            float2 x2 = bc[base + 2 * m];
            float2 x3 = bc[base + 3 * m];
            float a1 = PI2_N * (float)(j * ts);
            float s1, c1v, s2, c2v;
            __sincosf(a1, &s1, &c1v);
            __sincosf(a1 + a1, &s2, &c2v);
            float2 w1 = make_float2(c1v, s1);
            float2 w2 = make_float2(c2v, s2);
            float2 w3 = cmul(w1, w2);
            float2 o0, o1, o2, o3;
            radix4(x0, x1, x2, x3, w1, w2, w3, o0, o1, o2, o3);
            bc[base]         = o0;
            bc[base + m]     = o1;
            bc[base + 2 * m] = o2;
            bc[base + 3 * m] = o3;
        }
        m >>= 2; ts <<= 2;
        __syncthreads();
    }
    // final radix-2 stage (span 1, no twiddle)
    #pragma unroll
    for (int i = 0; i < 8; ++i) {
        int v = q + (i << 7);              // 0..1023
        float2 a = bc[2 * v];
        float2 d = bc[2 * v + 1];
        bc[2 * v]     = make_float2(a.x + d.x, a.y + d.y);
        bc[2 * v + 1] = make_float2(a.x - d.x, a.y - d.y);
    }
    __syncthreads();

    // write-out: LDS position p holds frequency k = digitrev(p)
    float* outb = out + (size_t)b * SS * DD;
    const int k2 = 8 * g + c;
    if (k2 == 0) {
        // packed column: Z = FFT(col0 + i*col512); unpack both real spectra
        #pragma unroll
        for (int i = 0; i < 16; ++i) {
            int k  = q + (i << 7);                 // 0..2047
            int kp = (SS - k) & (SS - 1);
            float2 Zk  = bc[permS(k)];
            float2 Zkp = bc[permS(kp)];
            outb[(size_t)k * DD]       = 0.5f * (Zk.x + Zkp.x);   // Re F0[k]
            outb[(size_t)k * DD + 512] = 0.5f * (Zk.y + Zkp.y);   // Re F512[k]
        }
    } else {
        // k2 in [1,511]: own column + Hermitian mirror (1024-k2)
        const int mcol = DD - k2;
        #pragma unroll
        for (int i = 0; i < 16; ++i) {
            int p = q + (i << 7);          // 0..2047
            float re = bc[p].x;
            int k = (p >> 9) | (((p >> 7) & 3) << 2) | (((p >> 5) & 3) << 4)
                  | (((p >> 3) & 3) << 6) | (((p >> 1) & 3) << 8) | ((p & 1) << 10);
            outb[(size_t)k * DD + k2] = re;
            outb[(size_t)((SS - k) & (SS - 1)) * DD + mcol] = re;
        }
    }
}

extern "C" void kernel_launch(void* const* d_in, const int* in_sizes, int n_in,
                              void* d_out, int out_size, void* d_ws, size_t ws_size,
                              hipStream_t stream) {
    const float* x = (const float*)d_in[0];
    float* out    = (float*)d_out;                        // Re(FFT2) : 16,777,216 floats
    float* visual = out + (size_t)BB * SS * DD;           // softmax  : 16,777,216 floats

    char* ws = (char*)d_ws;
    float2* V1     = (float2*)ws;                                        // 68,157,440 B
    float*  partial = (float*)(ws + (size_t)BB * SS * W520 * sizeof(float2));  // 256 KB
    float*  rsum    = partial + BB * 8 * DD;                             // 32 KB

    hipLaunchKernelGGL(k_sumexp_partial, dim3(256), dim3(256), 0, stream, x, partial);
    hipLaunchKernelGGL(k_sumexp_combine, dim3(32), dim3(256), 0, stream, partial, rsum);
    hipLaunchKernelGGL(k_fft_d, dim3(BB * SS), dim3(256), 0, stream, x, rsum, visual, V1);
    hipLaunchKernelGGL(k_fft_s, dim3(BB * 64), dim3(1024), 0, stream, V1, out);
}

// Round 4
// 104.083 us; speedup vs baseline: 1.7630x; 1.3340x over previous
//
#include <hip/hip_runtime.h>
#include <math.h>

#define BB 8
#define SS 2048
#define DD 1024
#define W520 520   // padded row width of half-spectrum V1 (cols 0..511 used; col0 packs (F0,F512))

__device__ __forceinline__ float2 cmul(float2 a, float2 b) {
    return make_float2(fmaf(a.x, b.x, -a.y * b.y), fmaf(a.x, b.y, a.y * b.x));
}
__device__ __forceinline__ float2 c_add(float2 a, float2 b){ return make_float2(a.x+b.x, a.y+b.y); }
__device__ __forceinline__ float2 c_sub(float2 a, float2 b){ return make_float2(a.x-b.x, a.y-b.y); }
__device__ __forceinline__ float2 c_mi(float2 a){ return make_float2(a.y, -a.x); }   // -i*a

// DFT-4: X[k] = sum_q x_q (-i)^{qk}
__device__ __forceinline__ void dft4(float2 c0, float2 c1, float2 c2, float2 c3,
                                     float2& o0, float2& o1, float2& o2, float2& o3) {
    float2 d0 = c_add(c0, c2), d1 = c_sub(c0, c2);
    float2 d2 = c_add(c1, c3), d3 = c_mi(c_sub(c1, c3));
    o0 = c_add(d0, d2); o1 = c_add(d1, d3); o2 = c_sub(d0, d2); o3 = c_sub(d1, d3);
}

// radix-4 butterfly with output twiddles (used by k_fft_d only)
__device__ __forceinline__ void radix4(float2 c0, float2 c1, float2 c2, float2 c3,
                                       float2 w1, float2 w2, float2 w3,
                                       float2& o0, float2& o1, float2& o2, float2& o3) {
    float2 d0 = c_add(c0, c2), d1 = c_sub(c0, c2);
    float2 d2 = c_add(c1, c3), d3 = c_mi(c_sub(c1, c3));
    o0 = c_add(d0, d2);
    o1 = cmul(w1, c_add(d1, d3));
    o2 = cmul(w2, c_sub(d0, d2));
    o3 = cmul(w3, c_sub(d1, d3));
}

// in-register DFT-16 (natural order in/out); twiddles are compile-time constants
__device__ __forceinline__ void dft16(float2* z) {
    float2 a[16];
    #pragma unroll
    for (int r0 = 0; r0 < 4; ++r0)
        dft4(z[r0], z[r0+4], z[r0+8], z[r0+12], a[4*r0], a[4*r0+1], a[4*r0+2], a[4*r0+3]);
    const float2 W1 = {0.9238795325f, -0.3826834324f};
    const float2 W2 = {0.7071067812f, -0.7071067812f};
    const float2 W3 = {0.3826834324f, -0.9238795325f};
    const float2 W6 = {-0.7071067812f, -0.7071067812f};
    const float2 W9 = {-0.9238795325f, 0.3826834324f};
    a[5]  = cmul(a[5],  W1); a[6]  = cmul(a[6],  W2); a[7]  = cmul(a[7],  W3);
    a[9]  = cmul(a[9],  W2); a[10] = c_mi(a[10]);     a[11] = cmul(a[11], W6);
    a[13] = cmul(a[13], W3); a[14] = cmul(a[14], W6); a[15] = cmul(a[15], W9);
    #pragma unroll
    for (int m = 0; m < 4; ++m)
        dft4(a[m], a[4+m], a[8+m], a[12+m], z[m], z[m+4], z[m+8], z[m+12]);
}

// in-register DFT-8 (natural order)
__device__ __forceinline__ void dft8(const float2* u, float2* X) {
    float2 A0,A1,A2,A3,B0,B1,B2,B3;
    dft4(u[0], u[2], u[4], u[6], A0, A1, A2, A3);
    dft4(u[1], u[3], u[5], u[7], B0, B1, B2, B3);
    const float r = 0.7071067812f;
    float2 W1B = make_float2(r*(B1.x + B1.y), r*(B1.y - B1.x));   // (r,-r)*B1
    float2 W2B = c_mi(B2);
    float2 W3B = make_float2(r*(B3.y - B3.x), -r*(B3.x + B3.y));  // (-r,-r)*B3
    X[0] = c_add(A0, B0);  X[4] = c_sub(A0, B0);
    X[1] = c_add(A1, W1B); X[5] = c_sub(A1, W1B);
    X[2] = c_add(A2, W2B); X[6] = c_sub(A2, W2B);
    X[3] = c_add(A3, W3B); X[7] = c_sub(A3, W3B);
}

// ---------------- K1a: partial sum of exp over s-chunks ----------------
__global__ __launch_bounds__(256) void k_sumexp_partial(const float* __restrict__ x,
                                                        float* __restrict__ partial) {
    int bid = blockIdx.x;                 // 256 blocks: b(8) x sc(8) x dt(4)
    int b  = bid >> 5;
    int sc = (bid >> 2) & 7;
    int dt = bid & 3;
    int d  = (dt << 8) + threadIdx.x;
    const float* xp = x + ((size_t)(b * SS + sc * 256)) * DD + d;
    float acc = 0.f;
    #pragma unroll 8
    for (int i = 0; i < 256; ++i)
        acc += __expf(xp[(size_t)i * DD]);
    partial[(b * 8 + sc) * DD + d] = acc;
}

// ---------------- K1b: combine partials -> reciprocal sums ----------------
__global__ __launch_bounds__(256) void k_sumexp_combine(const float* __restrict__ partial,
                                                        float* __restrict__ rsum) {
    int i = blockIdx.x * 256 + threadIdx.x;   // 8192 threads
    int b = i >> 10, d = i & (DD - 1);
    float s = 0.f;
    #pragma unroll
    for (int sc = 0; sc < 8; ++sc) s += partial[(b * 8 + sc) * DD + d];
    rsum[i] = 1.f / s;
}

// ---------------- K2: softmax finish + 1024-pt FFT along D ----------------
__global__ __launch_bounds__(256) void k_fft_d(const float* __restrict__ x,
                                               const float* __restrict__ rsum,
                                               float* __restrict__ visual,
                                               float2* __restrict__ V1) {
    __shared__ float2 bufA[DD];
    __shared__ float2 bufB[DD];
    __shared__ float2 tw[DD / 2];
    const int t = threadIdx.x;
    const int bid = blockIdx.x;            // b*2048 + s
    const int b = bid >> 11;

    #pragma unroll
    for (int i = 0; i < 2; ++i) {          // twiddle table W[t]=exp(-2pi i t/1024)
        int j = t + (i << 8);
        float sn, cs;
        __sincosf(-6.283185307179586f * (float)j / (float)DD, &sn, &cs);
        tw[j] = make_float2(cs, sn);
    }
    const float* xr = x + (size_t)bid * DD;
    const float* rs = rsum + b * DD;
    float* vr = visual + (size_t)bid * DD;
    #pragma unroll
    for (int c = 0; c < 4; ++c) {
        int d = t + (c << 8);
        float v = __expf(xr[d]) * rs[d];
        vr[d] = v;
        bufA[d] = make_float2(v, 0.f);
    }
    __syncthreads();

    float2* src = bufA; float2* dst = bufB;
    int m = 1;
    #pragma unroll
    for (int st = 0; st < 5; ++st) {       // 4^5 = 1024 (Stockham, natural-order out)
        int k  = t & (m - 1);
        int jm = t - k;                    // j*m, < 256
        float2 c0 = src[k + jm];
        float2 c1 = src[k + jm + 256];
        float2 c2 = src[k + jm + 512];
        float2 c3 = src[k + jm + 768];
        float2 w1 = tw[jm];
        float2 w2 = tw[2 * jm];
        float2 w3 = cmul(w1, w2);
        float2 o0, o1, o2, o3;
        radix4(c0, c1, c2, c3, w1, w2, w3, o0, o1, o2, o3);
        int o = k + 4 * jm;
        dst[o]         = o0;
        dst[o + m]     = o1;
        dst[o + 2 * m] = o2;
        dst[o + 3 * m] = o3;
        float2* tmp = src; src = dst; dst = tmp;
        m <<= 2;
        __syncthreads();
    }
    float2* outp = V1 + (size_t)bid * W520;
    // col 0 packs the two purely-real spectrum columns: (F[0].re, F[512].re)
    outp[t] = (t == 0) ? make_float2(src[0].x, src[512].x) : src[t];
    outp[t + 256] = src[t + 256];
}

// ---------------- K3: 2048-pt FFT along S for 8 columns ----------------
// Register-resident 3-level FFT: 2048 = 16 (reg) x 16 (reg) x 8 (reg),
// two LDS transposes between levels, 3 barriers total, stores from registers.
#define CS1 2072   // layout-1 column stride (float2): 129*16 rounded to ==8 mod 16
#define CS2 2232   // layout-2 column stride (float2): 280*7+17*15+15 rounded to ==8 mod 16
__global__ __launch_bounds__(1024, 4) void k_fft_s(const float2* __restrict__ V1,
                                                   float* __restrict__ out) {
    __shared__ float2 buf[8 * CS2];        // 142,848 B transpose scratch (two layouts)
    __shared__ float2 zp[SS];              // 16,384 B packed-col scratch (block g==0)
    const int t = threadIdx.x;             // 0..1023
    // XCD-chunk swizzle: adjacent g share output 64B lines -> same XCD L2
    const int b = blockIdx.x & 7;
    const int g = blockIdx.x >> 3;         // 0..63

    float2 z[16];
    // ---- load + level 1: DFT-16 over r (elements s = q + 128 r) ----
    {
        const int c = t & 7, q = t >> 3;   // column, 0..127
        const float2* srcp = V1 + (size_t)b * SS * W520 + 8 * g + c;
        #pragma unroll
        for (int r = 0; r < 16; ++r) z[r] = srcp[(q + 128 * r) * W520];
        dft16(z);
        float sn, cs;                       // y[k1] *= W2048^{q k1}
        __sincosf(-6.283185307179586f * (float)q / 2048.f, &sn, &cs);
        float2 w = make_float2(cs, sn), wk = w;
        #pragma unroll
        for (int k1 = 1; k1 < 16; ++k1) { z[k1] = cmul(z[k1], wk); wk = cmul(wk, w); }
        float2* p = buf + c * CS1 + q;     // layout1: c*CS1 + 129*k1 + q
        #pragma unroll
        for (int k1 = 0; k1 < 16; ++k1) p[129 * k1] = z[k1];
    }
    __syncthreads();

    // ---- level 2: DFT-16 over q2 (q = q1 + 8 q2) ----
    {
        const int k1 = t & 15, c = (t >> 4) & 7, q1 = t >> 7;
        const float2* p = buf + c * CS1 + 129 * k1 + q1;
        #pragma unroll
        for (int j = 0; j < 16; ++j) z[j] = p[8 * j];
        __syncthreads();                   // all layout1 reads done before layout2 writes
        dft16(z);
        float sn, cs;                       // v[k2a] *= W128^{q1 k2a}
        __sincosf(-6.283185307179586f * (float)q1 / 128.f, &sn, &cs);
        float2 w = make_float2(cs, sn), wk = w;
        #pragma unroll
        for (int a = 1; a < 16; ++a) { z[a] = cmul(z[a], wk); wk = cmul(wk, w); }
        float2* p2 = buf + c * CS2 + 280 * q1 + 17 * k1;   // layout2
        #pragma unroll
        for (int a = 0; a < 16; ++a) p2[a] = z[a];
    }
    __syncthreads();

    // ---- level 3: DFT-8 over q1, store from registers ----
    {
        const int c = t & 7, rest = t >> 3;
        const int k1 = rest & 15, k2h = rest >> 4;      // k2a = 2*k2h + e
        const int k2col = 8 * g + c;                    // 0..511
        float* outb = out + (size_t)b * SS * DD;
        const bool packed = (k2col == 0);
        #pragma unroll
        for (int e = 0; e < 2; ++e) {
            const int k2a = 2 * k2h + e;
            float2 u[8], X[8];
            const float2* p = buf + c * CS2 + 17 * k1 + k2a;
            #pragma unroll
            for (int q1 = 0; q1 < 8; ++q1) u[q1] = p[280 * q1];
            dft8(u, X);
            #pragma unroll
            for (int k2b = 0; k2b < 8; ++k2b) {
                const int k = k1 + 16 * k2a + 256 * k2b;
                if (packed) {
                    zp[k] = X[k2b];
                } else {
                    outb[(size_t)k * DD + k2col] = X[k2b].x;
                    outb[(size_t)((SS - k) & (SS - 1)) * DD + (DD - k2col)] = X[k2b].x;
                }
            }
        }
        // unpack the packed column (cols 0 and 512) — only block g==0
        if (g == 0) {
            __syncthreads();
            #pragma unroll
            for (int e = 0; e < 2; ++e) {
                const int k = t + (e << 10);
                const int km = (SS - k) & (SS - 1);
                float2 Zk = zp[k], Zm = zp[km];
                outb[(size_t)k * DD]       = 0.5f * (Zk.x + Zm.x);
                outb[(size_t)k * DD + 512] = 0.5f * (Zk.y + Zm.y);
            }
        }
    }
}

extern "C" void kernel_launch(void* const* d_in, const int* in_sizes, int n_in,
                              void* d_out, int out_size, void* d_ws, size_t ws_size,
                              hipStream_t stream) {
    const float* x = (const float*)d_in[0];
    float* out    = (float*)d_out;                        // Re(FFT2) : 16,777,216 floats
    float* visual = out + (size_t)BB * SS * DD;           // softmax  : 16,777,216 floats

    char* ws = (char*)d_ws;
    float2* V1     = (float2*)ws;                                        // 68,157,440 B
    float*  partial = (float*)(ws + (size_t)BB * SS * W520 * sizeof(float2));  // 256 KB
    float*  rsum    = partial + BB * 8 * DD;                             // 32 KB

    hipLaunchKernelGGL(k_sumexp_partial, dim3(256), dim3(256), 0, stream, x, partial);
    hipLaunchKernelGGL(k_sumexp_combine, dim3(32), dim3(256), 0, stream, partial, rsum);
    hipLaunchKernelGGL(k_fft_d, dim3(BB * SS), dim3(256), 0, stream, x, rsum, visual, V1);
    hipLaunchKernelGGL(k_fft_s, dim3(BB * 64), dim3(1024), 0, stream, V1, out);
}

// Round 5
// 103.655 us; speedup vs baseline: 1.7703x; 1.0041x over previous
//
#include <hip/hip_runtime.h>
#include <math.h>

#define BB 8
#define SS 2048
#define DD 1024
#define W520 520   // padded row width of half-spectrum V1 (cols 0..511 used; col0 packs (F0,F512))

__device__ __forceinline__ float2 cmul(float2 a, float2 b) {
    return make_float2(fmaf(a.x, b.x, -a.y * b.y), fmaf(a.x, b.y, a.y * b.x));
}
__device__ __forceinline__ float2 c_add(float2 a, float2 b){ return make_float2(a.x+b.x, a.y+b.y); }
__device__ __forceinline__ float2 c_sub(float2 a, float2 b){ return make_float2(a.x-b.x, a.y-b.y); }
__device__ __forceinline__ float2 c_mi(float2 a){ return make_float2(a.y, -a.x); }   // -i*a

// DFT-4: X[k] = sum_q x_q (-i)^{qk}
__device__ __forceinline__ void dft4(float2 c0, float2 c1, float2 c2, float2 c3,
                                     float2& o0, float2& o1, float2& o2, float2& o3) {
    float2 d0 = c_add(c0, c2), d1 = c_sub(c0, c2);
    float2 d2 = c_add(c1, c3), d3 = c_mi(c_sub(c1, c3));
    o0 = c_add(d0, d2); o1 = c_add(d1, d3); o2 = c_sub(d0, d2); o3 = c_sub(d1, d3);
}

// in-register DFT-16 (natural order in/out); twiddles are compile-time constants
__device__ __forceinline__ void dft16(float2* z) {
    float2 a[16];
    #pragma unroll
    for (int r0 = 0; r0 < 4; ++r0)
        dft4(z[r0], z[r0+4], z[r0+8], z[r0+12], a[4*r0], a[4*r0+1], a[4*r0+2], a[4*r0+3]);
    const float2 W1 = {0.9238795325f, -0.3826834324f};
    const float2 W2 = {0.7071067812f, -0.7071067812f};
    const float2 W3 = {0.3826834324f, -0.9238795325f};
    const float2 W6 = {-0.7071067812f, -0.7071067812f};
    const float2 W9 = {-0.9238795325f, 0.3826834324f};
    a[5]  = cmul(a[5],  W1); a[6]  = cmul(a[6],  W2); a[7]  = cmul(a[7],  W3);
    a[9]  = cmul(a[9],  W2); a[10] = c_mi(a[10]);     a[11] = cmul(a[11], W6);
    a[13] = cmul(a[13], W3); a[14] = cmul(a[14], W6); a[15] = cmul(a[15], W9);
    #pragma unroll
    for (int m = 0; m < 4; ++m)
        dft4(a[m], a[4+m], a[8+m], a[12+m], z[m], z[m+4], z[m+8], z[m+12]);
}

// in-register DFT-8 (natural order)
__device__ __forceinline__ void dft8(const float2* u, float2* X) {
    float2 A0,A1,A2,A3,B0,B1,B2,B3;
    dft4(u[0], u[2], u[4], u[6], A0, A1, A2, A3);
    dft4(u[1], u[3], u[5], u[7], B0, B1, B2, B3);
    const float r = 0.7071067812f;
    float2 W1B = make_float2(r*(B1.x + B1.y), r*(B1.y - B1.x));   // (r,-r)*B1
    float2 W2B = c_mi(B2);
    float2 W3B = make_float2(r*(B3.y - B3.x), -r*(B3.x + B3.y));  // (-r,-r)*B3
    X[0] = c_add(A0, B0);  X[4] = c_sub(A0, B0);
    X[1] = c_add(A1, W1B); X[5] = c_sub(A1, W1B);
    X[2] = c_add(A2, W2B); X[6] = c_sub(A2, W2B);
    X[3] = c_add(A3, W3B); X[7] = c_sub(A3, W3B);
}

// ---------------- K1a: partial sum of exp over s-chunks ----------------
__global__ __launch_bounds__(256) void k_sumexp_partial(const float* __restrict__ x,
                                                        float* __restrict__ partial) {
    int bid = blockIdx.x;                 // 256 blocks: b(8) x sc(8) x dt(4)
    int b  = bid >> 5;
    int sc = (bid >> 2) & 7;
    int dt = bid & 3;
    int d  = (dt << 8) + threadIdx.x;
    const float* xp = x + ((size_t)(b * SS + sc * 256)) * DD + d;
    float acc = 0.f;
    #pragma unroll 8
    for (int i = 0; i < 256; ++i)
        acc += __expf(xp[(size_t)i * DD]);
    partial[(b * 8 + sc) * DD + d] = acc;
}

// ---------------- K1b: combine partials -> reciprocal sums ----------------
__global__ __launch_bounds__(256) void k_sumexp_combine(const float* __restrict__ partial,
                                                        float* __restrict__ rsum) {
    int i = blockIdx.x * 256 + threadIdx.x;   // 8192 threads
    int b = i >> 10, d = i & (DD - 1);
    float s = 0.f;
    #pragma unroll
    for (int sc = 0; sc < 8; ++sc) s += partial[(b * 8 + sc) * DD + d];
    rsum[i] = 1.f / s;
}

// ---------------- K2: softmax finish + 1024-pt FFT along D ----------------
// Register-resident 3-level FFT: 1024 = 16 (reg) x 16 (reg) x 4 (reg).
// 4 rows per block, 256 threads (64 threads x 16 regs per row), 3 barriers.
#define RB 1040   // per-row LDS stride (float2): 16*65
__global__ __launch_bounds__(256, 4) void k_fft_d(const float* __restrict__ x,
                                                  const float* __restrict__ rsum,
                                                  float* __restrict__ visual,
                                                  float2* __restrict__ V1) {
    __shared__ float2 buf[4 * RB];         // 33,280 B -> 4 blocks/CU
    const int t = threadIdx.x;
    const int row = t >> 6;                // 0..3
    const int tr  = t & 63;
    const int s4  = blockIdx.x << 2;       // first row of this block
    const int b   = s4 >> 11;
    const float* rs = rsum + b * DD;
    float2* rbuf = buf + row * RB;

    float2 z[16];
    // ---- load + softmax finish + level 1: DFT-16 over r (d = q + 64 r) ----
    {
        const int q = tr;
        const float* xr = x + (size_t)(s4 + row) * DD;
        float* vr = visual + (size_t)(s4 + row) * DD;
        #pragma unroll
        for (int r = 0; r < 16; ++r) {
            int d = q + 64 * r;
            float v = __expf(xr[d]) * rs[d];
            vr[d] = v;
            z[r] = make_float2(v, 0.f);
        }
        dft16(z);
        float sn, cs;                       // y[k1] *= W1024^{q k1}
        __sincosf(-6.283185307179586f * (float)q / 1024.f, &sn, &cs);
        float2 w = make_float2(cs, sn), wk = w;
        #pragma unroll
        for (int k1 = 1; k1 < 16; ++k1) { z[k1] = cmul(z[k1], wk); wk = cmul(wk, w); }
        #pragma unroll
        for (int k1 = 0; k1 < 16; ++k1) rbuf[65 * k1 + q] = z[k1];
    }
    __syncthreads();
    // ---- level 2: DFT-16 over q2 (q = q1 + 4 q2), twiddle W64^{q1 k2a} ----
    {
        const int k1 = tr & 15, q1 = tr >> 4;      // q1 in 0..3
        const float2* p = rbuf + 65 * k1 + q1;
        #pragma unroll
        for (int j = 0; j < 16; ++j) z[j] = p[4 * j];
        __syncthreads();                   // all layout1 reads done before layout2 writes
        dft16(z);
        float sn, cs;
        __sincosf(-6.283185307179586f * (float)q1 / 64.f, &sn, &cs);
        float2 w = make_float2(cs, sn), wk = w;
        #pragma unroll
        for (int a = 1; a < 16; ++a) { z[a] = cmul(z[a], wk); wk = cmul(wk, w); }
        float2* p2 = rbuf + 65 * k1 + 16 * q1;     // layout2: 65*k1 + 16*q1 + k2a
        #pragma unroll
        for (int a = 0; a < 16; ++a) p2[a] = z[a];
    }
    __syncthreads();
    // ---- level 3: DFT-4 over q1; write V1 half-spectrum from registers ----
    {
        const int k1 = tr & 15, j = tr >> 4;       // j in 0..3, k2a = 4j + jj
        float2* outp = V1 + (size_t)(s4 + row) * W520;
        #pragma unroll
        for (int jj = 0; jj < 4; ++jj) {
            const int k2a = 4 * j + jj;
            const float2* p = rbuf + 65 * k1 + k2a;
            float2 X0, X1, X2, X3;
            dft4(p[0], p[16], p[32], p[48], X0, X1, X2, X3);   // over q1 (stride 16)
            const int kbase = k1 + 16 * k2a;       // = k for k2b=0; +256 -> k2b=1; +512 -> k2b=2
            if (kbase == 0) outp[0] = make_float2(X0.x, X2.x); // packed (Re F0, Re F512)
            else            outp[kbase] = X0;
            outp[kbase + 256] = X1;
        }
    }
}

// ---------------- K3: 2048-pt FFT along S for 4 columns ----------------
// Register-resident 3-level FFT (2048 = 16 x 16 x 8), 512 threads,
// LDS 71.4 KB -> 2 blocks/CU for cross-block phase overlap. Grid = 2 rounds.
#define CS1 2072   // layout-1 column stride (float2)
#define CS2 2232   // layout-2 column stride (float2)
__global__ __launch_bounds__(512, 4) void k_fft_s(const float2* __restrict__ V1,
                                                  float* __restrict__ out) {
    __shared__ float2 buf[4 * CS2];        // 71,424 B
    const int t = threadIdx.x;             // 0..511
    // XCD-chunk swizzle: same-b adjacent-G blocks (sharing 64B lines) -> same XCD
    const int b = blockIdx.x & 7;
    const int G = blockIdx.x >> 3;         // 0..127 ; columns 4G..4G+3

    float2 z[16];
    // ---- load + level 1: DFT-16 over r (elements s = q + 128 r) ----
    {
        const int c = t & 3, q = t >> 2;   // column 0..3, q 0..127
        const float2* srcp = V1 + (size_t)b * SS * W520 + 4 * G + c;
        #pragma unroll
        for (int r = 0; r < 16; ++r) z[r] = srcp[(q + 128 * r) * W520];
        dft16(z);
        float sn, cs;                       // y[k1] *= W2048^{q k1}
        __sincosf(-6.283185307179586f * (float)q / 2048.f, &sn, &cs);
        float2 w = make_float2(cs, sn), wk = w;
        #pragma unroll
        for (int k1 = 1; k1 < 16; ++k1) { z[k1] = cmul(z[k1], wk); wk = cmul(wk, w); }
        float2* p = buf + c * CS1 + q;     // layout1: c*CS1 + 129*k1 + q
        #pragma unroll
        for (int k1 = 0; k1 < 16; ++k1) p[129 * k1] = z[k1];
    }
    __syncthreads();

    // ---- level 2: DFT-16 over q2 (q = q1 + 8 q2) ----
    {
        const int k1 = t & 15, c = (t >> 4) & 3, q1 = t >> 6;   // q1 0..7
        const float2* p = buf + c * CS1 + 129 * k1 + q1;
        #pragma unroll
        for (int j = 0; j < 16; ++j) z[j] = p[8 * j];
        __syncthreads();                   // all layout1 reads done before layout2 writes
        dft16(z);
        float sn, cs;                       // v[k2a] *= W128^{q1 k2a}
        __sincosf(-6.283185307179586f * (float)q1 / 128.f, &sn, &cs);
        float2 w = make_float2(cs, sn), wk = w;
        #pragma unroll
        for (int a = 1; a < 16; ++a) { z[a] = cmul(z[a], wk); wk = cmul(wk, w); }
        float2* p2 = buf + c * CS2 + 280 * q1 + 17 * k1;   // layout2
        #pragma unroll
        for (int a = 0; a < 16; ++a) p2[a] = z[a];
    }
    __syncthreads();

    // ---- level 3: DFT-8 over q1, store from registers ----
    const int c = t & 3, rest = t >> 2;
    const int k1 = rest & 15, k2h = rest >> 4;      // k2h 0..7 ; k2a = 2*k2h + e
    const int k2col = 4 * G + c;                    // 0..511
    float* outb = out + (size_t)b * SS * DD;
    const bool packed = (k2col == 0);
    float2 zsave[16];                               // packed-thread X stash
    #pragma unroll
    for (int e = 0; e < 2; ++e) {
        const int k2a = 2 * k2h + e;
        float2 u[8], X[8];
        const float2* p = buf + c * CS2 + 17 * k1 + k2a;
        #pragma unroll
        for (int q1 = 0; q1 < 8; ++q1) u[q1] = p[280 * q1];
        dft8(u, X);
        #pragma unroll
        for (int k2b = 0; k2b < 8; ++k2b) {
            const int k = k1 + 16 * k2a + 256 * k2b;
            if (packed) {
                zsave[e * 8 + k2b] = X[k2b];
            } else {
                outb[(size_t)k * DD + k2col] = X[k2b].x;
                outb[(size_t)((SS - k) & (SS - 1)) * DD + (DD - k2col)] = X[k2b].x;
            }
        }
    }
    // unpack packed column (cols 0 and 512) — only block G==0, reusing buf
    if (G == 0) {
        __syncthreads();                   // everyone done reading layout2
        if (c == 0) {
            #pragma unroll
            for (int e = 0; e < 2; ++e)
                #pragma unroll
                for (int k2b = 0; k2b < 8; ++k2b)
                    buf[k1 + 16 * (2 * k2h + e) + 256 * k2b] = zsave[e * 8 + k2b];
        }
        __syncthreads();
        #pragma unroll
        for (int i = 0; i < 4; ++i) {
            const int k  = t + (i << 9);               // 0..2047
            const int km = (SS - k) & (SS - 1);
            float2 Zk = buf[k], Zm = buf[km];
            outb[(size_t)k * DD]       = 0.5f * (Zk.x + Zm.x);
            outb[(size_t)k * DD + 512] = 0.5f * (Zk.y + Zm.y);
        }
    }
}

extern "C" void kernel_launch(void* const* d_in, const int* in_sizes, int n_in,
                              void* d_out, int out_size, void* d_ws, size_t ws_size,
                              hipStream_t stream) {
    const float* x = (const float*)d_in[0];
    float* out    = (float*)d_out;                        // Re(FFT2) : 16,777,216 floats
    float* visual = out + (size_t)BB * SS * DD;           // softmax  : 16,777,216 floats

    char* ws = (char*)d_ws;
    float2* V1     = (float2*)ws;                                        // 68,157,440 B
    float*  partial = (float*)(ws + (size_t)BB * SS * W520 * sizeof(float2));  // 256 KB
    float*  rsum    = partial + BB * 8 * DD;                             // 32 KB

    hipLaunchKernelGGL(k_sumexp_partial, dim3(256), dim3(256), 0, stream, x, partial);
    hipLaunchKernelGGL(k_sumexp_combine, dim3(32), dim3(256), 0, stream, partial, rsum);
    hipLaunchKernelGGL(k_fft_d, dim3(BB * SS / 4), dim3(256), 0, stream, x, rsum, visual, V1);
    hipLaunchKernelGGL(k_fft_s, dim3(BB * 128), dim3(512), 0, stream, V1, out);
}

// Round 6
// 99.898 us; speedup vs baseline: 1.8369x; 1.0376x over previous
//
#include <hip/hip_runtime.h>
#include <math.h>

#define BB 8
#define SS 2048
#define DD 1024
// V1 layout: [b][g][s][c] with column k2 = 4*g + c (g<128, c<4); col 0 packs (Re F0, Re F512)

__device__ __forceinline__ float2 cmul(float2 a, float2 b) {
    return make_float2(fmaf(a.x, b.x, -a.y * b.y), fmaf(a.x, b.y, a.y * b.x));
}
__device__ __forceinline__ float2 c_add(float2 a, float2 b){ return make_float2(a.x+b.x, a.y+b.y); }
__device__ __forceinline__ float2 c_sub(float2 a, float2 b){ return make_float2(a.x-b.x, a.y-b.y); }
__device__ __forceinline__ float2 c_mi(float2 a){ return make_float2(a.y, -a.x); }   // -i*a

// DFT-4: X[k] = sum_q x_q (-i)^{qk}
__device__ __forceinline__ void dft4(float2 c0, float2 c1, float2 c2, float2 c3,
                                     float2& o0, float2& o1, float2& o2, float2& o3) {
    float2 d0 = c_add(c0, c2), d1 = c_sub(c0, c2);
    float2 d2 = c_add(c1, c3), d3 = c_mi(c_sub(c1, c3));
    o0 = c_add(d0, d2); o1 = c_add(d1, d3); o2 = c_sub(d0, d2); o3 = c_sub(d1, d3);
}

// in-register DFT-16 (natural order in/out); twiddles are compile-time constants
__device__ __forceinline__ void dft16(float2* z) {
    float2 a[16];
    #pragma unroll
    for (int r0 = 0; r0 < 4; ++r0)
        dft4(z[r0], z[r0+4], z[r0+8], z[r0+12], a[4*r0], a[4*r0+1], a[4*r0+2], a[4*r0+3]);
    const float2 W1 = {0.9238795325f, -0.3826834324f};
    const float2 W2 = {0.7071067812f, -0.7071067812f};
    const float2 W3 = {0.3826834324f, -0.9238795325f};
    const float2 W6 = {-0.7071067812f, -0.7071067812f};
    const float2 W9 = {-0.9238795325f, 0.3826834324f};
    a[5]  = cmul(a[5],  W1); a[6]  = cmul(a[6],  W2); a[7]  = cmul(a[7],  W3);
    a[9]  = cmul(a[9],  W2); a[10] = c_mi(a[10]);     a[11] = cmul(a[11], W6);
    a[13] = cmul(a[13], W3); a[14] = cmul(a[14], W6); a[15] = cmul(a[15], W9);
    #pragma unroll
    for (int m = 0; m < 4; ++m)
        dft4(a[m], a[4+m], a[8+m], a[12+m], z[m], z[m+4], z[m+8], z[m+12]);
}

// in-register DFT-8 (natural order)
__device__ __forceinline__ void dft8(const float2* u, float2* X) {
    float2 A0,A1,A2,A3,B0,B1,B2,B3;
    dft4(u[0], u[2], u[4], u[6], A0, A1, A2, A3);
    dft4(u[1], u[3], u[5], u[7], B0, B1, B2, B3);
    const float r = 0.7071067812f;
    float2 W1B = make_float2(r*(B1.x + B1.y), r*(B1.y - B1.x));   // (r,-r)*B1
    float2 W2B = c_mi(B2);
    float2 W3B = make_float2(r*(B3.y - B3.x), -r*(B3.x + B3.y));  // (-r,-r)*B3
    X[0] = c_add(A0, B0);  X[4] = c_sub(A0, B0);
    X[1] = c_add(A1, W1B); X[5] = c_sub(A1, W1B);
    X[2] = c_add(A2, W2B); X[6] = c_sub(A2, W2B);
    X[3] = c_add(A3, W3B); X[7] = c_sub(A3, W3B);
}

// ---------------- K1a: partial sum of exp over s-chunks ----------------
__global__ __launch_bounds__(256) void k_sumexp_partial(const float* __restrict__ x,
                                                        float* __restrict__ partial) {
    int bid = blockIdx.x;                 // 256 blocks: b(8) x sc(8) x dt(4)
    int b  = bid >> 5;
    int sc = (bid >> 2) & 7;
    int dt = bid & 3;
    int d  = (dt << 8) + threadIdx.x;
    const float* xp = x + ((size_t)(b * SS + sc * 256)) * DD + d;
    float acc = 0.f;
    #pragma unroll 8
    for (int i = 0; i < 256; ++i)
        acc += __expf(xp[(size_t)i * DD]);
    partial[(b * 8 + sc) * DD + d] = acc;
}

// ---------------- K1b: combine partials -> reciprocal sums ----------------
__global__ __launch_bounds__(256) void k_sumexp_combine(const float* __restrict__ partial,
                                                        float* __restrict__ rsum) {
    int i = blockIdx.x * 256 + threadIdx.x;   // 8192 threads
    int b = i >> 10, d = i & (DD - 1);
    float s = 0.f;
    #pragma unroll
    for (int sc = 0; sc < 8; ++sc) s += partial[(b * 8 + sc) * DD + d];
    rsum[i] = 1.f / s;
}

// ---------------- K2: softmax finish + 1024-pt FFT along D ----------------
// Register-resident 3-level FFT: 1024 = 16 (reg) x 16 (reg) x 4 (reg).
// 4 rows per block, 256 threads (64 threads x 16 regs per row), 3 barriers.
#define RB 1040   // per-row LDS stride (float2): 16*65
__global__ __launch_bounds__(256, 4) void k_fft_d(const float* __restrict__ x,
                                                  const float* __restrict__ rsum,
                                                  float* __restrict__ visual,
                                                  float2* __restrict__ V1) {
    __shared__ float2 buf[4 * RB];         // 33,280 B -> 4 blocks/CU
    const int t = threadIdx.x;
    const int row = t >> 6;                // 0..3
    const int tr  = t & 63;
    const int s4  = blockIdx.x << 2;       // first row of this block (global)
    const int b   = s4 >> 11;
    const int sl  = (s4 & (SS - 1)) + row; // row within batch
    const float* rs = rsum + b * DD;
    float2* rbuf = buf + row * RB;

    float2 z[16];
    // ---- load + softmax finish + level 1: DFT-16 over r (d = q + 64 r) ----
    {
        const int q = tr;
        const float* xr = x + (size_t)(s4 + row) * DD;
        float* vr = visual + (size_t)(s4 + row) * DD;
        #pragma unroll
        for (int r = 0; r < 16; ++r) {
            int d = q + 64 * r;
            float v = __expf(xr[d]) * rs[d];
            vr[d] = v;
            z[r] = make_float2(v, 0.f);
        }
        dft16(z);
        float sn, cs;                       // y[k1] *= W1024^{q k1}
        __sincosf(-6.283185307179586f * (float)q / 1024.f, &sn, &cs);
        float2 w = make_float2(cs, sn), wk = w;
        #pragma unroll
        for (int k1 = 1; k1 < 16; ++k1) { z[k1] = cmul(z[k1], wk); wk = cmul(wk, w); }
        #pragma unroll
        for (int k1 = 0; k1 < 16; ++k1) rbuf[65 * k1 + q] = z[k1];
    }
    __syncthreads();
    // ---- level 2: DFT-16 over q2 (q = q1 + 4 q2), twiddle W64^{q1 k2a} ----
    {
        const int k1 = tr & 15, q1 = tr >> 4;      // q1 in 0..3
        const float2* p = rbuf + 65 * k1 + q1;
        #pragma unroll
        for (int j = 0; j < 16; ++j) z[j] = p[4 * j];
        __syncthreads();                   // all layout1 reads done before layout2 writes
        dft16(z);
        float sn, cs;
        __sincosf(-6.283185307179586f * (float)q1 / 64.f, &sn, &cs);
        float2 w = make_float2(cs, sn), wk = w;
        #pragma unroll
        for (int a = 1; a < 16; ++a) { z[a] = cmul(z[a], wk); wk = cmul(wk, w); }
        float2* p2 = rbuf + 65 * k1 + 16 * q1;     // layout2: 65*k1 + 16*q1 + k2a
        #pragma unroll
        for (int a = 0; a < 16; ++a) p2[a] = z[a];
    }
    __syncthreads();
    // ---- level 3: DFT-4 over q1; write V1 (grouped layout) from registers ----
    {
        const int k1 = tr & 15, j = tr >> 4;       // j in 0..3, k2a = 4j + jj
        // V1 grouped: addr = ((b*128 + (k2>>2))*SS + sl)*4 + (k2&3)
        float2* v1b = V1 + ((size_t)b * 128 * SS + sl) * 4;
        #pragma unroll
        for (int jj = 0; jj < 4; ++jj) {
            const int k2a = 4 * j + jj;
            const float2* p = rbuf + 65 * k1 + k2a;
            float2 X0, X1, X2, X3;
            dft4(p[0], p[16], p[32], p[48], X0, X1, X2, X3);   // over q1 (stride 16)
            const int kb = k1 + 16 * k2a;          // col for k2b=0; +256 -> k2b=1; +512 -> k2b=2
            float2 v0 = (kb == 0) ? make_float2(X0.x, X2.x)    // packed (Re F0, Re F512)
                                  : X0;
            v1b[(size_t)(kb >> 2) * (SS * 4) + (kb & 3)] = v0;
            const int kb1 = kb + 256;
            v1b[(size_t)(kb1 >> 2) * (SS * 4) + (kb1 & 3)] = X1;
        }
    }
}

// ---------------- K3: 2048-pt FFT along S for 4 columns ----------------
// Register-resident 3-level FFT (2048 = 16 x 16 x 8), 512 threads,
// LDS 71.4 KB -> 2 blocks/CU. Grouped V1 layout => perfectly contiguous loads.
// Packed column (k2=0) spectrum goes to Zcol scratch; k_unpack finishes it.
#define CS1 2072   // layout-1 column stride (float2)
#define CS2 2232   // layout-2 column stride (float2)
__global__ __launch_bounds__(512, 4) void k_fft_s(const float2* __restrict__ V1,
                                                  float* __restrict__ out,
                                                  float2* __restrict__ Zcol) {
    __shared__ float2 buf[4 * CS2];        // 71,424 B
    const int t = threadIdx.x;             // 0..511
    // XCD-chunk swizzle: same-b adjacent-G blocks (sharing output 64B lines) -> same XCD
    const int b = blockIdx.x & 7;
    const int G = blockIdx.x >> 3;         // 0..127 ; columns 4G..4G+3

    float2 z[16];
    // ---- load + level 1: DFT-16 over r (elements s = q + 128 r) ----
    {
        const int c = t & 3, q = t >> 2;   // column 0..3, q 0..127
        const float2* srcp = V1 + (size_t)(b * 128 + G) * (SS * 4);
        #pragma unroll
        for (int r = 0; r < 16; ++r) z[r] = srcp[t + 512 * r];   // fully contiguous
        dft16(z);
        float sn, cs;                       // y[k1] *= W2048^{q k1}
        __sincosf(-6.283185307179586f * (float)q / 2048.f, &sn, &cs);
        float2 w = make_float2(cs, sn), wk = w;
        #pragma unroll
        for (int k1 = 1; k1 < 16; ++k1) { z[k1] = cmul(z[k1], wk); wk = cmul(wk, w); }
        float2* p = buf + c * CS1 + q;     // layout1: c*CS1 + 129*k1 + q
        #pragma unroll
        for (int k1 = 0; k1 < 16; ++k1) p[129 * k1] = z[k1];
    }
    __syncthreads();

    // ---- level 2: DFT-16 over q2 (q = q1 + 8 q2) ----
    {
        const int k1 = t & 15, c = (t >> 4) & 3, q1 = t >> 6;   // q1 0..7
        const float2* p = buf + c * CS1 + 129 * k1 + q1;
        #pragma unroll
        for (int j = 0; j < 16; ++j) z[j] = p[8 * j];
        __syncthreads();                   // all layout1 reads done before layout2 writes
        dft16(z);
        float sn, cs;                       // v[k2a] *= W128^{q1 k2a}
        __sincosf(-6.283185307179586f * (float)q1 / 128.f, &sn, &cs);
        float2 w = make_float2(cs, sn), wk = w;
        #pragma unroll
        for (int a = 1; a < 16; ++a) { z[a] = cmul(z[a], wk); wk = cmul(wk, w); }
        float2* p2 = buf + c * CS2 + 280 * q1 + 17 * k1;   // layout2
        #pragma unroll
        for (int a = 0; a < 16; ++a) p2[a] = z[a];
    }
    __syncthreads();

    // ---- level 3: DFT-8 over q1, store from registers ----
    const int c = t & 3, rest = t >> 2;
    const int k1 = rest & 15, k2h = rest >> 4;      // k2h 0..7 ; k2a = 2*k2h + e
    const int k2col = 4 * G + c;                    // 0..511
    float* outb = out + (size_t)b * SS * DD;
    float2* Zb = Zcol + b * SS;
    const bool packed = (k2col == 0);
    #pragma unroll
    for (int e = 0; e < 2; ++e) {
        const int k2a = 2 * k2h + e;
        float2 u[8], X[8];
        const float2* p = buf + c * CS2 + 17 * k1 + k2a;
        #pragma unroll
        for (int q1 = 0; q1 < 8; ++q1) u[q1] = p[280 * q1];
        dft8(u, X);
        #pragma unroll
        for (int k2b = 0; k2b < 8; ++k2b) {
            const int k = k1 + 16 * k2a + 256 * k2b;
            if (packed) {
                Zb[k] = X[k2b];                     // packed spectrum -> scratch
            } else {
                outb[(size_t)k * DD + k2col] = X[k2b].x;
                outb[(size_t)((SS - k) & (SS - 1)) * DD + (DD - k2col)] = X[k2b].x;
            }
        }
    }
}

// ---------------- K4: unpack packed column -> out cols 0 and 512 ----------------
__global__ __launch_bounds__(256) void k_unpack(const float2* __restrict__ Zcol,
                                                float* __restrict__ out) {
    const int b = blockIdx.x;              // 8 blocks
    const float2* Z = Zcol + b * SS;
    float* outb = out + (size_t)b * SS * DD;
    #pragma unroll
    for (int i = 0; i < 8; ++i) {
        int k  = threadIdx.x + (i << 8);
        int km = (SS - k) & (SS - 1);
        float2 Zk = Z[k], Zm = Z[km];
        outb[(size_t)k * DD]       = 0.5f * (Zk.x + Zm.x);
        outb[(size_t)k * DD + 512] = 0.5f * (Zk.y + Zm.y);
    }
}

extern "C" void kernel_launch(void* const* d_in, const int* in_sizes, int n_in,
                              void* d_out, int out_size, void* d_ws, size_t ws_size,
                              hipStream_t stream) {
    const float* x = (const float*)d_in[0];
    float* out    = (float*)d_out;                        // Re(FFT2) : 16,777,216 floats
    float* visual = out + (size_t)BB * SS * DD;           // softmax  : 16,777,216 floats

    char* ws = (char*)d_ws;
    float2* V1   = (float2*)ws;                                  // 64 MiB (grouped layout)
    float2* Zcol = (float2*)(ws + (size_t)BB * 128 * SS * 4 * sizeof(float2));  // 128 KiB
    float* partial = (float*)(Zcol + BB * SS);                   // 256 KiB
    float* rsum    = partial + BB * 8 * DD;                      // 32 KiB

    hipLaunchKernelGGL(k_sumexp_partial, dim3(256), dim3(256), 0, stream, x, partial);
    hipLaunchKernelGGL(k_sumexp_combine, dim3(32), dim3(256), 0, stream, partial, rsum);
    hipLaunchKernelGGL(k_fft_d, dim3(BB * SS / 4), dim3(256), 0, stream, x, rsum, visual, V1);
    hipLaunchKernelGGL(k_fft_s, dim3(BB * 128), dim3(512), 0, stream, V1, out, Zcol);
    hipLaunchKernelGGL(k_unpack, dim3(BB), dim3(256), 0, stream, Zcol, out);
}

// Round 7
// 94.377 us; speedup vs baseline: 1.9443x; 1.0585x over previous
//
#include <hip/hip_runtime.h>
#include <math.h>

#define BB 8
#define SS 2048
#define DD 1024
// V1 layout: [b][g][s][c] with column k2 = 4*g + c (g<128, c<4); col 0 packs (Re F0, Re F512)

__device__ __forceinline__ float2 cmul(float2 a, float2 b) {
    return make_float2(fmaf(a.x, b.x, -a.y * b.y), fmaf(a.x, b.y, a.y * b.x));
}
__device__ __forceinline__ float2 c_add(float2 a, float2 b){ return make_float2(a.x+b.x, a.y+b.y); }
__device__ __forceinline__ float2 c_sub(float2 a, float2 b){ return make_float2(a.x-b.x, a.y-b.y); }
__device__ __forceinline__ float2 c_mi(float2 a){ return make_float2(a.y, -a.x); }   // -i*a

// DFT-4: X[k] = sum_q x_q (-i)^{qk}
__device__ __forceinline__ void dft4(float2 c0, float2 c1, float2 c2, float2 c3,
                                     float2& o0, float2& o1, float2& o2, float2& o3) {
    float2 d0 = c_add(c0, c2), d1 = c_sub(c0, c2);
    float2 d2 = c_add(c1, c3), d3 = c_mi(c_sub(c1, c3));
    o0 = c_add(d0, d2); o1 = c_add(d1, d3); o2 = c_sub(d0, d2); o3 = c_sub(d1, d3);
}

// in-register DFT-16 (natural order in/out); twiddles are compile-time constants
__device__ __forceinline__ void dft16(float2* z) {
    float2 a[16];
    #pragma unroll
    for (int r0 = 0; r0 < 4; ++r0)
        dft4(z[r0], z[r0+4], z[r0+8], z[r0+12], a[4*r0], a[4*r0+1], a[4*r0+2], a[4*r0+3]);
    const float2 W1 = {0.9238795325f, -0.3826834324f};
    const float2 W2 = {0.7071067812f, -0.7071067812f};
    const float2 W3 = {0.3826834324f, -0.9238795325f};
    const float2 W6 = {-0.7071067812f, -0.7071067812f};
    const float2 W9 = {-0.9238795325f, 0.3826834324f};
    a[5]  = cmul(a[5],  W1); a[6]  = cmul(a[6],  W2); a[7]  = cmul(a[7],  W3);
    a[9]  = cmul(a[9],  W2); a[10] = c_mi(a[10]);     a[11] = cmul(a[11], W6);
    a[13] = cmul(a[13], W3); a[14] = cmul(a[14], W6); a[15] = cmul(a[15], W9);
    #pragma unroll
    for (int m = 0; m < 4; ++m)
        dft4(a[m], a[4+m], a[8+m], a[12+m], z[m], z[m+4], z[m+8], z[m+12]);
}

// in-register DFT-8 (natural order)
__device__ __forceinline__ void dft8(const float2* u, float2* X) {
    float2 A0,A1,A2,A3,B0,B1,B2,B3;
    dft4(u[0], u[2], u[4], u[6], A0, A1, A2, A3);
    dft4(u[1], u[3], u[5], u[7], B0, B1, B2, B3);
    const float r = 0.7071067812f;
    float2 W1B = make_float2(r*(B1.x + B1.y), r*(B1.y - B1.x));   // (r,-r)*B1
    float2 W2B = c_mi(B2);
    float2 W3B = make_float2(r*(B3.y - B3.x), -r*(B3.x + B3.y));  // (-r,-r)*B3
    X[0] = c_add(A0, B0);  X[4] = c_sub(A0, B0);
    X[1] = c_add(A1, W1B); X[5] = c_sub(A1, W1B);
    X[2] = c_add(A2, W2B); X[6] = c_sub(A2, W2B);
    X[3] = c_add(A3, W3B); X[7] = c_sub(A3, W3B);
}

// ---------------- K1a: partial sum of exp over s-chunks ----------------
// float4 loads (16B/lane, 8KB in flight at unroll 8), 512 blocks = 2/CU.
__global__ __launch_bounds__(256) void k_sumexp_partial(const float* __restrict__ x,
                                                        float* __restrict__ partial) {
    int bid = blockIdx.x;                 // 512 blocks: b(8) x sc(64)
    int b  = bid >> 6;
    int sc = bid & 63;                    // 32 rows per chunk
    const float4* xp = (const float4*)(x + ((size_t)(b * SS + sc * 32)) * DD) + threadIdx.x;
    float4 acc = make_float4(0.f, 0.f, 0.f, 0.f);
    #pragma unroll 8
    for (int i = 0; i < 32; ++i) {
        float4 v = xp[(size_t)i * (DD / 4)];
        acc.x += __expf(v.x); acc.y += __expf(v.y);
        acc.z += __expf(v.z); acc.w += __expf(v.w);
    }
    ((float4*)(partial + (size_t)(b * 64 + sc) * DD))[threadIdx.x] = acc;
}

// ---------------- K1b: combine partials -> reciprocal sums ----------------
__global__ __launch_bounds__(256) void k_sumexp_combine(const float* __restrict__ partial,
                                                        float* __restrict__ rsum) {
    int i = blockIdx.x * 256 + threadIdx.x;   // 8192 threads
    int b = i >> 10, d = i & (DD - 1);
    float s = 0.f;
    #pragma unroll 8
    for (int sc = 0; sc < 64; ++sc) s += partial[(size_t)(b * 64 + sc) * DD + d];
    rsum[i] = 1.f / s;
}

// ---------------- K2: softmax finish + 1024-pt FFT along D ----------------
// Register-resident 3-level FFT: 1024 = 16 (reg) x 16 (reg) x 4 (reg).
// 4 rows per block, 256 threads (64 threads x 16 regs per row), 3 barriers.
#define RB 1040   // per-row LDS stride (float2): 16*65
__global__ __launch_bounds__(256, 4) void k_fft_d(const float* __restrict__ x,
                                                  const float* __restrict__ rsum,
                                                  float* __restrict__ visual,
                                                  float2* __restrict__ V1) {
    __shared__ float2 buf[4 * RB];         // 33,280 B -> 4 blocks/CU
    const int t = threadIdx.x;
    const int row = t >> 6;                // 0..3
    const int tr  = t & 63;
    const int s4  = blockIdx.x << 2;       // first row of this block (global)
    const int b   = s4 >> 11;
    const int sl  = (s4 & (SS - 1)) + row; // row within batch
    const float* rs = rsum + b * DD;
    float2* rbuf = buf + row * RB;

    float2 z[16];
    // ---- load + softmax finish + level 1: DFT-16 over r (d = q + 64 r) ----
    {
        const int q = tr;
        const float* xr = x + (size_t)(s4 + row) * DD;
        float* vr = visual + (size_t)(s4 + row) * DD;
        #pragma unroll
        for (int r = 0; r < 16; ++r) {
            int d = q + 64 * r;
            float v = __expf(xr[d]) * rs[d];
            vr[d] = v;
            z[r] = make_float2(v, 0.f);
        }
        dft16(z);
        float sn, cs;                       // y[k1] *= W1024^{q k1}
        __sincosf(-6.283185307179586f * (float)q / 1024.f, &sn, &cs);
        float2 w = make_float2(cs, sn), wk = w;
        #pragma unroll
        for (int k1 = 1; k1 < 16; ++k1) { z[k1] = cmul(z[k1], wk); wk = cmul(wk, w); }
        #pragma unroll
        for (int k1 = 0; k1 < 16; ++k1) rbuf[65 * k1 + q] = z[k1];
    }
    __syncthreads();
    // ---- level 2: DFT-16 over q2 (q = q1 + 4 q2), twiddle W64^{q1 k2a} ----
    {
        const int k1 = tr & 15, q1 = tr >> 4;      // q1 in 0..3
        const float2* p = rbuf + 65 * k1 + q1;
        #pragma unroll
        for (int j = 0; j < 16; ++j) z[j] = p[4 * j];
        __syncthreads();                   // all layout1 reads done before layout2 writes
        dft16(z);
        float sn, cs;
        __sincosf(-6.283185307179586f * (float)q1 / 64.f, &sn, &cs);
        float2 w = make_float2(cs, sn), wk = w;
        #pragma unroll
        for (int a = 1; a < 16; ++a) { z[a] = cmul(z[a], wk); wk = cmul(wk, w); }
        float2* p2 = rbuf + 65 * k1 + 16 * q1;     // layout2: 65*k1 + 16*q1 + k2a
        #pragma unroll
        for (int a = 0; a < 16; ++a) p2[a] = z[a];
    }
    __syncthreads();
    // ---- level 3: DFT-4 over q1; write V1 (grouped layout) from registers ----
    {
        const int k1 = tr & 15, j = tr >> 4;       // j in 0..3, k2a = 4j + jj
        // V1 grouped: addr = ((b*128 + (k2>>2))*SS + sl)*4 + (k2&3)
        float2* v1b = V1 + ((size_t)b * 128 * SS + sl) * 4;
        #pragma unroll
        for (int jj = 0; jj < 4; ++jj) {
            const int k2a = 4 * j + jj;
            const float2* p = rbuf + 65 * k1 + k2a;
            float2 X0, X1, X2, X3;
            dft4(p[0], p[16], p[32], p[48], X0, X1, X2, X3);   // over q1 (stride 16)
            const int kb = k1 + 16 * k2a;          // col for k2b=0; +256 -> k2b=1; +512 -> k2b=2
            float2 v0 = (kb == 0) ? make_float2(X0.x, X2.x)    // packed (Re F0, Re F512)
                                  : X0;
            v1b[(size_t)(kb >> 2) * (SS * 4) + (kb & 3)] = v0;
            const int kb1 = kb + 256;
            v1b[(size_t)(kb1 >> 2) * (SS * 4) + (kb1 & 3)] = X1;
        }
    }
}

// ---------------- K3: 2048-pt FFT along S for 4 columns ----------------
// Register-resident 3-level FFT (2048 = 16 x 16 x 8), 512 threads,
// LDS 71.4 KB -> 2 blocks/CU. Grouped V1 layout => perfectly contiguous loads.
// Packed column (k2=0): spectrum -> Zcol scratch; the SAME block (G==0) reads
// it back after __syncthreads (vmcnt drained) and unpacks cols 0/512 in a tail.
#define CS1 2072   // layout-1 column stride (float2)
#define CS2 2232   // layout-2 column stride (float2)
__global__ __launch_bounds__(512, 4) void k_fft_s(const float2* __restrict__ V1,
                                                  float* __restrict__ out,
                                                  float2* __restrict__ Zcol) {
    __shared__ float2 buf[4 * CS2];        // 71,424 B
    const int t = threadIdx.x;             // 0..511
    // XCD-chunk swizzle: same-b adjacent-G blocks (sharing output 64B lines) -> same XCD
    const int b = blockIdx.x & 7;
    const int G = blockIdx.x >> 3;         // 0..127 ; columns 4G..4G+3

    float2 z[16];
    // ---- load + level 1: DFT-16 over r (elements s = q + 128 r) ----
    {
        const int c = t & 3, q = t >> 2;   // column 0..3, q 0..127
        const float2* srcp = V1 + (size_t)(b * 128 + G) * (SS * 4);
        #pragma unroll
        for (int r = 0; r < 16; ++r) z[r] = srcp[t + 512 * r];   // fully contiguous
        dft16(z);
        float sn, cs;                       // y[k1] *= W2048^{q k1}
        __sincosf(-6.283185307179586f * (float)q / 2048.f, &sn, &cs);
        float2 w = make_float2(cs, sn), wk = w;
        #pragma unroll
        for (int k1 = 1; k1 < 16; ++k1) { z[k1] = cmul(z[k1], wk); wk = cmul(wk, w); }
        float2* p = buf + c * CS1 + q;     // layout1: c*CS1 + 129*k1 + q
        #pragma unroll
        for (int k1 = 0; k1 < 16; ++k1) p[129 * k1] = z[k1];
    }
    __syncthreads();

    // ---- level 2: DFT-16 over q2 (q = q1 + 8 q2) ----
    {
        const int k1 = t & 15, c = (t >> 4) & 3, q1 = t >> 6;   // q1 0..7
        const float2* p = buf + c * CS1 + 129 * k1 + q1;
        #pragma unroll
        for (int j = 0; j < 16; ++j) z[j] = p[8 * j];
        __syncthreads();                   // all layout1 reads done before layout2 writes
        dft16(z);
        float sn, cs;                       // v[k2a] *= W128^{q1 k2a}
        __sincosf(-6.283185307179586f * (float)q1 / 128.f, &sn, &cs);
        float2 w = make_float2(cs, sn), wk = w;
        #pragma unroll
        for (int a = 1; a < 16; ++a) { z[a] = cmul(z[a], wk); wk = cmul(wk, w); }
        float2* p2 = buf + c * CS2 + 280 * q1 + 17 * k1;   // layout2
        #pragma unroll
        for (int a = 0; a < 16; ++a) p2[a] = z[a];
    }
    __syncthreads();

    // ---- level 3: DFT-8 over q1, store from registers ----
    const int c = t & 3, rest = t >> 2;
    const int k1 = rest & 15, k2h = rest >> 4;      // k2h 0..7 ; k2a = 2*k2h + e
    const int k2col = 4 * G + c;                    // 0..511
    float* outb = out + (size_t)b * SS * DD;
    float2* Zb = Zcol + b * SS;
    const bool packed = (k2col == 0);
    #pragma unroll
    for (int e = 0; e < 2; ++e) {
        const int k2a = 2 * k2h + e;
        float2 u[8], X[8];
        const float2* p = buf + c * CS2 + 17 * k1 + k2a;
        #pragma unroll
        for (int q1 = 0; q1 < 8; ++q1) u[q1] = p[280 * q1];
        dft8(u, X);
        #pragma unroll
        for (int k2b = 0; k2b < 8; ++k2b) {
            const int k = k1 + 16 * k2a + 256 * k2b;
            if (packed) {
                Zb[k] = X[k2b];                     // packed spectrum -> scratch
            } else {
                outb[(size_t)k * DD + k2col] = X[k2b].x;
                outb[(size_t)((SS - k) & (SS - 1)) * DD + (DD - k2col)] = X[k2b].x;
            }
        }
    }
    // ---- tail (G==0 only): unpack packed column -> out cols 0 and 512 ----
    // Zb was written entirely by THIS block; __syncthreads drains vmcnt(0),
    // so the reads below see the completed writes (same CU, L1-coherent).
    if (G == 0) {
        __syncthreads();
        #pragma unroll
        for (int i = 0; i < 4; ++i) {
            const int k  = t + (i << 9);           // 0..2047
            const int km = (SS - k) & (SS - 1);
            float2 Zk = Zb[k], Zm = Zb[km];
            outb[(size_t)k * DD]       = 0.5f * (Zk.x + Zm.x);
            outb[(size_t)k * DD + 512] = 0.5f * (Zk.y + Zm.y);
        }
    }
}

extern "C" void kernel_launch(void* const* d_in, const int* in_sizes, int n_in,
                              void* d_out, int out_size, void* d_ws, size_t ws_size,
                              hipStream_t stream) {
    const float* x = (const float*)d_in[0];
    float* out    = (float*)d_out;                        // Re(FFT2) : 16,777,216 floats
    float* visual = out + (size_t)BB * SS * DD;           // softmax  : 16,777,216 floats

    char* ws = (char*)d_ws;
    float2* V1   = (float2*)ws;                                  // 64 MiB (grouped layout)
    float2* Zcol = (float2*)(ws + (size_t)BB * 128 * SS * 4 * sizeof(float2));  // 128 KiB
    float* partial = (float*)(Zcol + BB * SS);                   // 2 MiB (8 x 64 x 1024)
    float* rsum    = partial + (size_t)BB * 64 * DD;             // 32 KiB

    hipLaunchKernelGGL(k_sumexp_partial, dim3(BB * 64), dim3(256), 0, stream, x, partial);
    hipLaunchKernelGGL(k_sumexp_combine, dim3(32), dim3(256), 0, stream, partial, rsum);
    hipLaunchKernelGGL(k_fft_d, dim3(BB * SS / 4), dim3(256), 0, stream, x, rsum, visual, V1);
    hipLaunchKernelGGL(k_fft_s, dim3(BB * 128), dim3(512), 0, stream, V1, out, Zcol);
}